// Round 4
// baseline (1134.164 us; speedup 1.0000x reference)
//
#include <hip/hip_runtime.h>

// GPUHungarianMatcher R13 — exact replication of the reference's degenerate
// "_lsa" (minv reset every inner iteration => chain-Dijkstra). One block
// (4 waves) per batch. R13 = R12 + two LATENCY-chain attacks (R12's lesson:
// spine is latency-bound at 33% issue occupancy; issue-count trims are free
// but worthless):
//  (A) mailbox carries the winner's cd (R10's idea, conflict-free layout):
//      cd lives in owner-thread REGISTERS (cdu/cdx/cdy[8]); after the intra-
//      lane argmin, a static mux tree (independent of the key/DPP chain —
//      hides in its ~96cy of stalls) selects the lane's candidate cd; the
//      winning lane writes a 32B mailbox {khi,klo,bidx | u_lo,u_hi,tx,ty}.
//      Post-barrier: 8 independent broadcast b128 reads + tournament. The
//      DEPENDENT colDat read (~130cy/step on the spine) is deleted, and so
//      is the LDS colDat array. Register refresh at row end goes through
//      SoA scatter slots slotU(f64)/slotX/slotY(f32) whose owner-apply
//      reads are stride-8B/4B = conflict-free (R10's 530K conflict cycles
//      came from its [8][256]x16B AoS slots — that layout is the bug fixed
//      here).
//  (B) barrier-graph thinning, all proof-grade:
//      * barrier E deleted: waves are lockstep (the break decision is
//        computed from identical mailbox data), so no wave is mid-step when
//        another enters the epilogue; the only cross-access (p[recCol] write
//        vs the final step's p[j1] read) races on a DEAD value (i0 is
//        discarded on break).
//      * S==1 rows (step 0 hits a free column) skip the epilogue entirely:
//        unew = recU+(Dfin-recD) = 0+(D-0) = D bitwise (D != -0.0: 0+x can
//        only produce -0 from (-0)+(-0)); the owner thread of j1 updates its
//        own registers and writes p[j1], ordered by the NEXT row's step-0
//        barrier (ds_write precedes the owner's barrier arrival; syncthreads
//        drains lgkmcnt). No scatter slots were touched, so nothing to apply.
//      * mailbox parity is GLOBAL (toggles every step, never resets per
//        row): reuse of a parity slot across barrier-less row boundaries
//        would need a wave 2 steps behind — impossible with 1 barrier/step.
//
// Exactness invariants (unchanged from the R2-R12 absmax-0 lineage):
//  * cost fp32: fabsf(qx-tX)+fabsf(qy-tY)+np_, reduced fp64: ((double)cf-u)-v
//  * scans read only PRE-search u/v (register cd/v refreshed only at row
//    boundaries; usedMask prevents re-selection within a row)
//  * argmin: fmin + smallest-k among exact equals (ctz of ==-mask) =
//    np.argmin first occurrence; +inf f32 poison for used columns (R12)
//  * pairwise tournament: left wins ties at every level => same winner as
//    the left-to-right scan (min + earliest index, keys lexicographic)
//  * u update: single add of prefix-difference on pre-search u (recU)
//  * v update: vdelta scatter, values bitwise-identical to the serial loop
//  * softmax bitwise-identical to the R2 tree (same thread mapping)
//  * free-flag: cdx = -1.0f iff column unmatched (real tx >= 0; slot
//    sentinel -2.0f = "not written this row")

constexpr int B = 8;
constexpr int Q = 2048;        // columns (queries)
constexpr int T = 256;         // rows (targets)
constexpr int NT = 256;        // threads per block (4 waves)
constexpr int KPT = Q / NT;    // 8 columns per thread, j = 1 + tid + k*256
constexpr int NW = NT / 64;

__device__ __forceinline__ unsigned wave_min_u32_dpp(unsigned a) {
  // full-wave u32 min: row_shr 1,2,4,8 then row_bcast15, row_bcast31;
  // invalid source lanes keep old (bound_ctrl=false, masks 0xf) = identity.
  int v = (int)a, t;
  t = __builtin_amdgcn_update_dpp(v, v, 0x111, 0xf, 0xf, false);
  v = ((unsigned)t < (unsigned)v) ? t : v;
  t = __builtin_amdgcn_update_dpp(v, v, 0x112, 0xf, 0xf, false);
  v = ((unsigned)t < (unsigned)v) ? t : v;
  t = __builtin_amdgcn_update_dpp(v, v, 0x114, 0xf, 0xf, false);
  v = ((unsigned)t < (unsigned)v) ? t : v;
  t = __builtin_amdgcn_update_dpp(v, v, 0x118, 0xf, 0xf, false);
  v = ((unsigned)t < (unsigned)v) ? t : v;
  t = __builtin_amdgcn_update_dpp(v, v, 0x142, 0xf, 0xf, false);
  v = ((unsigned)t < (unsigned)v) ? t : v;
  t = __builtin_amdgcn_update_dpp(v, v, 0x143, 0xf, 0xf, false);
  v = ((unsigned)t < (unsigned)v) ? t : v;
  return (unsigned)__builtin_amdgcn_readlane(v, 63);   // lane 63 = global min
}

__launch_bounds__(NT, 1)
__global__ void hungarian_r13(const float* __restrict__ outs,
                              const float* __restrict__ tgts,
                              int* __restrict__ out) {
  const int b = blockIdx.x;
  const int tid = threadIdx.x;
  const int lane = tid & 63;
  const int wv = tid >> 6;

  __shared__ float2 rowTgt[T + 1];  // rowTgt[r] = {tx[r-1], ty[r-1]} (read-only)
  __shared__ short p[Q + 1];        // p[j]: row matched to col j (1-based), 0 free
  __shared__ uint4 pk2[2][NW][2];   // mailbox (global parity):
                                    //   [.][w][0] = {khi, klo, bidx, 0}
                                    //   [.][w][1] = {u_lo, u_hi, tx, ty}
  __shared__ double vdelta[Q];      // per-column v-delta scatter; 0.0 = no update
  __shared__ double slotU[Q];       // per-column cd-u scatter (SoA, 8B stride)
  __shared__ float slotX[Q];        // per-column cd-tx scatter; -2.0f = unwritten
  __shared__ float slotY[Q];        // per-column cd-ty scatter
  __shared__ int ansArr[T];
  __shared__ double s_rv[NW];
  __shared__ float sh_f;

  const size_t qbase = (size_t)b * Q;
  const size_t tbase = (size_t)b * T;

  // ---- stage per-thread column data (fixed mapping j = 1 + tid + k*256) ----
  float xs[KPT], qx[KPT], qy[KPT];
#pragma unroll
  for (int k = 0; k < KPT; ++k) {
    const size_t o = (qbase + tid + k * NT) * 3;
    xs[k] = outs[o];
    qx[k] = outs[o + 1];
    qy[k] = outs[o + 2];
  }
  {
    const size_t o = (tbase + tid) * 3;   // T == NT: one target per thread
    rowTgt[tid + 1] = make_float2(tgts[o + 1], tgts[o + 2]);
    if (tid == 0) rowTgt[0] = make_float2(0.f, 0.f);
  }

  // ---- softmax over Q logits (bitwise-identical to the R2-passing tree) ----
  float lmax = xs[0];
#pragma unroll
  for (int k = 1; k < KPT; ++k) lmax = fmaxf(lmax, xs[k]);
  for (int off = 32; off > 0; off >>= 1) lmax = fmaxf(lmax, __shfl_down(lmax, off));
  if ((tid & 63) == 0) s_rv[tid >> 6] = (double)lmax;
  __syncthreads();
  if (tid == 0) {
    float m2 = (float)s_rv[0];
    for (int w = 1; w < NW; ++w) m2 = fmaxf(m2, (float)s_rv[w]);
    sh_f = m2;
  }
  __syncthreads();
  const float smax = sh_f;
  float ex[KPT];
  float lsum = 0.f;
#pragma unroll
  for (int k = 0; k < KPT; ++k) { ex[k] = expf(xs[k] - smax); lsum += ex[k]; }
  for (int off = 32; off > 0; off >>= 1) lsum += __shfl_down(lsum, off);
  if ((tid & 63) == 0) s_rv[tid >> 6] = (double)lsum;
  __syncthreads();
  if (tid == 0) {
    float s2 = 0.f;
    for (int w = 0; w < NW; ++w) s2 += (float)s_rv[w];
    sh_f = s2;
  }
  __syncthreads();
  const float ssum = sh_f;
  float np_[KPT];
#pragma unroll
  for (int k = 0; k < KPT; ++k) np_[k] = -(ex[k] / ssum);

  // ---- init state ----
  for (int j = tid; j <= Q; j += NT) p[j] = 0;
  double vreg[KPT];                 // v[j] for this thread's 8 columns
  double cdu[KPT];                  // u[p[j]] register cache
  float cdx[KPT], cdy[KPT];         // tx/ty[p[j]-1] cache; -1.0f = FREE column
#pragma unroll
  for (int k = 0; k < KPT; ++k) {
    vreg[k] = 0.0;
    cdu[k] = 0.0; cdx[k] = -1.0f; cdy[k] = 0.0f;
    const int a = tid + (k << 8);
    vdelta[a] = 0.0;
    slotU[a] = 0.0; slotX[a] = -2.0f; slotY[a] = 0.0f;
  }
  __syncthreads();

  const float FINF = __int_as_float(0x7f800000);   // +inf poison for used cols
  float2 nxtT = rowTgt[1];                         // prefetch row 1's target
  int par = 0;                                     // GLOBAL mailbox parity

  // ---- main loop over rows ----
  for (int i = 1; i <= T; ++i) {
    unsigned usedMask = 0;
    double D = 0.0;
    int i0 = i;
    double ui0 = 0.0;                // u[i] == 0 at row i's search start (R12)
    float tX = nxtT.x, tY = nxtT.y;  // prefetched during previous row's tail
    int s = 0, S;
    int j1v = 0;                         // column selected at the previous step
    int recRow = 0, recCol = 0, recPrev = 0;   // thread t records step t's state
    double recU = 0.0, recD = 0.0;
    float recTX = 0.f, recTY = 0.f;

    for (;;) {
      const int cpar = par; par ^= 1;   // global parity (uniform: lockstep)

      // record this step's pre-state on thread s (off the dependency spine)
      if (tid == s) {
        recRow = i0; recU = ui0; recTX = tX; recTY = tY; recD = D; recPrev = j1v;
      }

      // scan my 8 columns: cur = ((double)cf - u[i0]) - v[j]; used columns
      // poisoned at the f32 stage (cf = +inf => cur = +inf, never wins)
      double cv[KPT];
#pragma unroll
      for (int k = 0; k < KPT; ++k) {
        float cf = fabsf(qx[k] - tX) + fabsf(qy[k] - tY) + np_[k];
        if (usedMask & (1u << k)) cf = FINF;
        cv[k] = ((double)cf - ui0) - vreg[k];
      }
      // within-lane argmin: fmin tree for the value, then parallel ==-mask +
      // ctz => smallest k among exact equals (first occurrence; +/-0 match)
      const double m01 = fmin(cv[0], cv[1]), m23 = fmin(cv[2], cv[3]);
      const double m45 = fmin(cv[4], cv[5]), m67 = fmin(cv[6], cv[7]);
      const double m03 = fmin(m01, m23), m47 = fmin(m45, m67);
      double bval = fmin(m03, m47);
      unsigned emsk = 0;
#pragma unroll
      for (int k = 0; k < KPT; ++k) emsk |= (cv[k] == bval) ? (1u << k) : 0u;
      const int bk = (int)__builtin_ctz(emsk);   // emsk != 0 always
      int bidx = 1 + tid + (bk << 8);

      // per-lane cd[bk] static mux tree — independent of the key/DPP chain,
      // issues inside its stall window (values valid even for used columns)
      const int b0 = bk & 1, b1 = (bk >> 1) & 1, b2 = (bk >> 2) & 1;
      const double uA = b0 ? cdu[1] : cdu[0], uB = b0 ? cdu[3] : cdu[2];
      const double uC = b0 ? cdu[5] : cdu[4], uD = b0 ? cdu[7] : cdu[6];
      const float xA = b0 ? cdx[1] : cdx[0], xB = b0 ? cdx[3] : cdx[2];
      const float xC = b0 ? cdx[5] : cdx[4], xD = b0 ? cdx[7] : cdx[6];
      const float yA = b0 ? cdy[1] : cdy[0], yB = b0 ? cdy[3] : cdy[2];
      const float yC = b0 ? cdy[5] : cdy[4], yD = b0 ? cdy[7] : cdy[6];
      const double uE = b1 ? uB : uA, uF = b1 ? uD : uC;
      const float xE = b1 ? xB : xA, xF = b1 ? xD : xC;
      const float yE = b1 ? yB : yA, yF = b1 ? yD : yC;
      const double csu = b2 ? uF : uE;
      const float csx = b2 ? xF : xE;
      const float csy = b2 ? yF : yE;

      // monotonic u64 bit-key of the per-lane winner (canonicalize -0 -> +0)
      bval += 0.0;
      const long long bb = __double_as_longlong(bval);
      const unsigned long long key = (unsigned long long)bb ^
          ((bb < 0) ? 0xFFFFFFFFFFFFFFFFull : 0x8000000000000000ull);
      const unsigned khi = (unsigned)(key >> 32);
      const unsigned klo = (unsigned)key;

      // wave argmin: DPP min on hi32, ballot for winner, exact ties slow path
      const unsigned minhi = wave_min_u32_dpp(khi);
      const unsigned long long mask = __ballot(khi == minhi);
      int wl;
      if (__popcll(mask) == 1) {
        wl = (int)__ffsll(mask) - 1;
      } else {
        unsigned wklo = 0xffffffffu; int widx = 0x7fffffff; wl = 0;
        unsigned long long mm = mask;
        while (mm) {
          const int l = (int)__ffsll(mm) - 1; mm &= mm - 1;
          const unsigned lo2 = (unsigned)__builtin_amdgcn_readlane((int)klo, l);
          const int ix2 = __builtin_amdgcn_readlane(bidx, l);
          if (lo2 < wklo || (lo2 == wklo && ix2 < widx)) {
            wklo = lo2; widx = ix2; wl = l;
          }
        }
      }
      // the WINNING LANE writes keys + its candidate's cd (32B, 2x b128)
      if (lane == wl) {
        pk2[cpar][wv][0] = make_uint4(minhi, klo, (unsigned)bidx, 0u);
        const unsigned long long cu =
            (unsigned long long)__double_as_longlong(csu);
        pk2[cpar][wv][1] = make_uint4((unsigned)cu, (unsigned)(cu >> 32),
                                      __float_as_uint(csx),
                                      __float_as_uint(csy));
      }
      __syncthreads();            // the only per-step barrier

      // read all 8 mailbox quads (independent, wave-uniform broadcast reads)
      const uint4 c0v = pk2[cpar][0][0];
      const uint4 c1v = pk2[cpar][1][0];
      const uint4 c2v = pk2[cpar][2][0];
      const uint4 c3v = pk2[cpar][3][0];
      const uint4 d0v = pk2[cpar][0][1];
      const uint4 d1v = pk2[cpar][1][1];
      const uint4 d2v = pk2[cpar][2][1];
      const uint4 d3v = pk2[cpar][3][1];

      // cross-wave pairwise tournament (left wins ties at every level ==
      // same winner as the left-to-right scan of R5-R12)
      const unsigned long long k0b = ((unsigned long long)c0v.x << 32) | c0v.y;
      const unsigned long long k1b = ((unsigned long long)c1v.x << 32) | c1v.y;
      const unsigned long long k2b = ((unsigned long long)c2v.x << 32) | c2v.y;
      const unsigned long long k3b = ((unsigned long long)c3v.x << 32) | c3v.y;
      const int j0b = (int)c0v.z, j1bb = (int)c1v.z;
      const int j2b = (int)c2v.z, j3b = (int)c3v.z;
      // level 1 (pairs 01 and 23, independent)
      const bool w01 = (k1b < k0b) || (k1b == k0b && j1bb < j0b);
      const unsigned long long k01 = w01 ? k1b : k0b;
      const int j01 = w01 ? j1bb : j0b;
      const bool w23 = (k3b < k2b) || (k3b == k2b && j3b < j2b);
      const unsigned long long k23 = w23 ? k3b : k2b;
      const int j23 = w23 ? j3b : j2b;
      // level 2 (final)
      const bool wf = (k23 < k01) || (k23 == k01 && j23 < j01);
      const unsigned long long bkk = wf ? k23 : k01;
      const int j1 = wf ? j23 : j01;          // selected column, 1-based
      // cd folded along the same tournament, in the u32 domain (12 cndmask)
      const unsigned ulA = w01 ? d1v.x : d0v.x, uhA = w01 ? d1v.y : d0v.y;
      const unsigned xAf = w01 ? d1v.z : d0v.z, yAf = w01 ? d1v.w : d0v.w;
      const unsigned ulB = w23 ? d3v.x : d2v.x, uhB = w23 ? d3v.y : d2v.y;
      const unsigned xBf = w23 ? d3v.z : d2v.z, yBf = w23 ? d3v.w : d2v.w;
      const unsigned ulW = wf ? ulB : ulA, uhW = wf ? uhB : uhA;
      const unsigned xW = wf ? xBf : xAf, yW = wf ? yBf : yAf;
      const double cdun = __longlong_as_double(
          (long long)(((unsigned long long)uhW << 32) | ulW));
      const float cdtx = __uint_as_float(xW);
      const float cdty = __uint_as_float(yW);

      // invert bit-key -> delta (bitwise identical on every thread)
      const long long db = (long long)((bkk & 0x8000000000000000ull)
                                           ? (bkk ^ 0x8000000000000000ull) : ~bkk);
      D += __longlong_as_double(db);
      if (tid == ((j1 - 1) & 255)) usedMask |= 1u << ((j1 - 1) >> 8);
      if (tid == s) recCol = j1;
      const int pj1 = (int)p[j1];   // off-path: feeds only next step's recorder
      j1v = j1;                     // (dead value on the final step)
      ++s;
      if (cdtx < 0.0f) { S = s; break; }   // free column => path complete
      ui0 = cdun; tX = cdtx; tY = cdty; i0 = pj1;
    }

    // ---- row tail: no E barrier (waves are lockstep; see header proof) ----
    nxtT = rowTgt[i < T ? i + 1 : T];   // prefetch next row's target (read-only)
    if (S == 1) {
      // fast path: step 0 hit a free column. unew = 0 + (D - 0) = D bitwise
      // (D != -0.0). Owner updates its own registers; p[j1] write is ordered
      // by the next row's step-0 barrier (lgkmcnt drained before s_barrier).
      const int c = j1v - 1;
      if (tid == (c & 255)) {
        p[j1v] = (short)i;
        const int ok = c >> 8;
#pragma unroll
        for (int k = 0; k < KPT; ++k) {
          if (k == ok) { cdu[k] = D; cdx[k] = tX; cdy[k] = tY; }
        }
      }
      // no scatter slots touched; nothing to apply, no barrier needed
    } else {
      const double Dfin = D;
      if (tid < S) {
        p[recCol] = (short)recRow;                // augment (rows/cols distinct)
        const double unew = recU + (Dfin - recD); // same single-add as R3-R12
        const int c = recCol - 1;
        slotU[c] = unew;                          // SoA cd scatter (conflict-
        slotX[c] = recTX;                         //  free owner reads)
        slotY[c] = recTY;
        if (tid >= 1) {
          // column of step tid-1 (== visCol[tid]) receives Dfin - recD
          // (== Dfin - visD[tid]); path columns distinct => no collision
          vdelta[recPrev - 1] = Dfin - recD;
        }
      }
      __syncthreads();              // F: scatter writes visible
      // owners apply their 8 slots: static reg indices; vdelta/slotU 8B
      // stride = 2-way (free), slotX/slotY 4B stride = conflict-free.
      // 0.0 vdelta is a bitwise no-op; slotX sentinel -2 = no cd update.
#pragma unroll
      for (int k = 0; k < KPT; ++k) {
        const int a = tid + (k << 8);
        const double dv = vdelta[a];
        const float sx = slotX[a];
        const double su = slotU[a];
        const float sy = slotY[a];
        vreg[k] -= dv;
        vdelta[a] = 0.0;            // reset; ordered vs next scatter by the
        slotX[a] = -2.0f;           //  next row's step barriers (>= 1 of them)
        const bool upd = (sx > -1.5f);
        cdu[k] = upd ? su : cdu[k];
        cdx[k] = upd ? sx : cdx[k];
        cdy[k] = upd ? sy : cdy[k];
      }
    }
  }
  __syncthreads();

  // ---- extract assignment, rank-sort (distinct values), write int32 ----
  for (int j = 1 + tid; j <= Q; j += NT) {
    const int pi = (int)p[j];
    if (pi > 0) ansArr[pi - 1] = j - 1;
  }
  __syncthreads();
  const int a = ansArr[tid];
  int rank = 0;
  for (int t2 = 0; t2 < T; ++t2) rank += (ansArr[t2] < a) ? 1 : 0;
  out[(size_t)b * T + rank] = a;                      // row_ind (sorted query idx)
  out[(size_t)B * T + (size_t)b * T + rank] = tid;    // col_ind (target idx)
}

extern "C" void kernel_launch(void* const* d_in, const int* in_sizes, int n_in,
                              void* d_out, int out_size, void* d_ws, size_t ws_size,
                              hipStream_t stream) {
  const float* outs = (const float*)d_in[0];   // (8, 2048, 3) fp32
  const float* tgts = (const float*)d_in[1];   // (8, 256, 3) fp32
  int* out = (int*)d_out;                      // row_ind (8,256) ++ col_ind (8,256)
  hungarian_r13<<<B, NT, 0, stream>>>(outs, tgts, out);
}

// Round 5
// 864.601 us; speedup vs baseline: 1.3118x; 1.3118x over previous
//
#include <hip/hip_runtime.h>

// GPUHungarianMatcher R14 — exact replication of the reference's degenerate
// "_lsa" (minv reset every inner iteration => chain-Dijkstra). One block
// (4 waves) per batch. R14 = R12 (validated spine + trims + vdelta scatter
// epilogue) + ONE latency-chain cut, informed by the R10/R13 post-mortems:
//
//   The post-barrier serial pair  pk read (~130cy) -> DEPENDENT colDat read
//   (~130cy)  is the largest spine item. R10/R13 removed it by caching cd in
//   registers, but paid ~80us for a 42-op pre-barrier mux tree and ~100us
//   for a fat (48 LDS-op) epilogue refresh. R14 gets the same cut for free:
//     * each lane issues  myCd = colDat[bidx]  for ITS OWN candidate right
//       after the intra-lane argmin — off the serial chain (latency hides
//       under the ~100cy DPP+ballot phase). Bank-clean: addresses are
//       16B-stride in tid plus bk*4096B (4096 % 128 == 0, bank-aligned), the
//       canonical contiguous-b128 pattern.
//     * the winning lane (it already holds colDat[bidx_wl] in registers)
//       writes a 32B mailbox {khi,klo,bidx | u_lo,u_hi,tx,ty}.
//     * post-barrier: 8 INDEPENDENT uniform b128 reads + key tournament +
//       12-cndmask u32 cd-fold. Serial chain ~190cy vs R11/R12's ~290cy.
//   colDat stays in LDS; the epilogue is byte-identical to R12 (colDat
//   write + vdelta scatter + 16-op apply). No register cd cache, no mux
//   tree, no slotU/X/Y.
//
// Exactness invariants (unchanged from the R2-R12 absmax-0 lineage):
//  * cost fp32: fabsf(qx-tX)+fabsf(qy-tY)+np_, reduced fp64: ((double)cf-u)-v
//  * scans read only PRE-search u/v (path rows/cols distinct, p injective);
//    colDat is read-only during a row's steps (written only in epilogues),
//    so the pre-barrier read returns exactly what R11 read post-barrier
//  * argmin: fmin + smallest-k among exact equals (ctz of ==-mask) =
//    np.argmin first occurrence; +inf f32 poison for used columns (R12);
//    a wave can never be all-used (used < 256 < 512 cols/wave) so the wave
//    winner is always a finite free column
//  * pairwise tournament: left wins ties at every level => same winner as
//    the left-to-right scan (min + earliest index, keys lexicographic);
//    cd folded along the same selectors in the u32 domain = bitwise equal
//  * u update: single add of prefix-difference on pre-search u (recU)
//  * v update: vdelta scatter, values bitwise-identical to the serial loop
//  * softmax bitwise-identical to the R2 tree (same thread mapping)
//  * free-flag: colDat[j].tx = -1.0f iff column j unmatched (real tx >= 0)

constexpr int B = 8;
constexpr int Q = 2048;        // columns (queries)
constexpr int T = 256;         // rows (targets)
constexpr int NT = 256;        // threads per block (4 waves)
constexpr int KPT = Q / NT;    // 8 columns per thread, j = 1 + tid + k*256
constexpr int NW = NT / 64;

struct __align__(16) CD { double u; float tx, ty; };   // one ds_read_b128

__device__ __forceinline__ unsigned wave_min_u32_dpp(unsigned a) {
  // full-wave u32 min: row_shr 1,2,4,8 then row_bcast15, row_bcast31;
  // invalid source lanes keep old (bound_ctrl=false, masks 0xf) = identity.
  int v = (int)a, t;
  t = __builtin_amdgcn_update_dpp(v, v, 0x111, 0xf, 0xf, false);
  v = ((unsigned)t < (unsigned)v) ? t : v;
  t = __builtin_amdgcn_update_dpp(v, v, 0x112, 0xf, 0xf, false);
  v = ((unsigned)t < (unsigned)v) ? t : v;
  t = __builtin_amdgcn_update_dpp(v, v, 0x114, 0xf, 0xf, false);
  v = ((unsigned)t < (unsigned)v) ? t : v;
  t = __builtin_amdgcn_update_dpp(v, v, 0x118, 0xf, 0xf, false);
  v = ((unsigned)t < (unsigned)v) ? t : v;
  t = __builtin_amdgcn_update_dpp(v, v, 0x142, 0xf, 0xf, false);
  v = ((unsigned)t < (unsigned)v) ? t : v;
  t = __builtin_amdgcn_update_dpp(v, v, 0x143, 0xf, 0xf, false);
  v = ((unsigned)t < (unsigned)v) ? t : v;
  return (unsigned)__builtin_amdgcn_readlane(v, 63);   // lane 63 = global min
}

__launch_bounds__(NT, 1)
__global__ void hungarian_r14(const float* __restrict__ outs,
                              const float* __restrict__ tgts,
                              int* __restrict__ out) {
  const int b = blockIdx.x;
  const int tid = threadIdx.x;
  const int lane = tid & 63;
  const int wv = tid >> 6;

  __shared__ CD colDat[Q + 1];      // colDat[j] = {u[p[j]], tx[p[j]-1], ty[p[j]-1]}
                                    // tx = -1.0f marks a FREE column
  __shared__ float2 rowTgt[T + 1];  // rowTgt[r] = {tx[r-1], ty[r-1]} (read-only)
  __shared__ short p[Q + 1];        // p[j]: row matched to col j (1-based), 0 free
  __shared__ uint4 pk2[2][NW][2];   // mailbox (parity = s&1):
                                    //   [.][w][0] = {khi, klo, bidx, 0}
                                    //   [.][w][1] = {u_lo, u_hi, tx, ty}
  __shared__ double vdelta[Q];      // per-column v-delta scatter; 0.0 = no update
  __shared__ int ansArr[T];
  __shared__ double s_rv[NW];
  __shared__ float sh_f;

  const size_t qbase = (size_t)b * Q;
  const size_t tbase = (size_t)b * T;

  // ---- stage per-thread column data (fixed mapping j = 1 + tid + k*256) ----
  float xs[KPT], qx[KPT], qy[KPT];
#pragma unroll
  for (int k = 0; k < KPT; ++k) {
    const size_t o = (qbase + tid + k * NT) * 3;
    xs[k] = outs[o];
    qx[k] = outs[o + 1];
    qy[k] = outs[o + 2];
  }
  {
    const size_t o = (tbase + tid) * 3;   // T == NT: one target per thread
    rowTgt[tid + 1] = make_float2(tgts[o + 1], tgts[o + 2]);
    if (tid == 0) rowTgt[0] = make_float2(0.f, 0.f);
  }

  // ---- softmax over Q logits (bitwise-identical to the R2-passing tree) ----
  float lmax = xs[0];
#pragma unroll
  for (int k = 1; k < KPT; ++k) lmax = fmaxf(lmax, xs[k]);
  for (int off = 32; off > 0; off >>= 1) lmax = fmaxf(lmax, __shfl_down(lmax, off));
  if ((tid & 63) == 0) s_rv[tid >> 6] = (double)lmax;
  __syncthreads();
  if (tid == 0) {
    float m2 = (float)s_rv[0];
    for (int w = 1; w < NW; ++w) m2 = fmaxf(m2, (float)s_rv[w]);
    sh_f = m2;
  }
  __syncthreads();
  const float smax = sh_f;
  float ex[KPT];
  float lsum = 0.f;
#pragma unroll
  for (int k = 0; k < KPT; ++k) { ex[k] = expf(xs[k] - smax); lsum += ex[k]; }
  for (int off = 32; off > 0; off >>= 1) lsum += __shfl_down(lsum, off);
  if ((tid & 63) == 0) s_rv[tid >> 6] = (double)lsum;
  __syncthreads();
  if (tid == 0) {
    float s2 = 0.f;
    for (int w = 0; w < NW; ++w) s2 += (float)s_rv[w];
    sh_f = s2;
  }
  __syncthreads();
  const float ssum = sh_f;
  float np_[KPT];
#pragma unroll
  for (int k = 0; k < KPT; ++k) np_[k] = -(ex[k] / ssum);

  // ---- init state ----
  for (int j = tid; j <= Q; j += NT) {
    p[j] = 0;
    CD c0; c0.u = 0.0; c0.tx = -1.0f; c0.ty = 0.0f;   // all columns free
    colDat[j] = c0;
  }
  double vreg[KPT];   // v[j] for this thread's 8 columns (static indices only)
#pragma unroll
  for (int k = 0; k < KPT; ++k) {
    vreg[k] = 0.0;
    vdelta[tid + (k << 8)] = 0.0;
  }
  __syncthreads();

  const float FINF = __int_as_float(0x7f800000);   // +inf poison for used cols
  float2 nxtT = rowTgt[1];                         // prefetch row 1's target

  // ---- main loop over rows ----
  for (int i = 1; i <= T; ++i) {
    unsigned usedMask = 0;
    double D = 0.0;
    int i0 = i;
    double ui0 = 0.0;                // u[i] == 0 at row i's search start (R12)
    float tX = nxtT.x, tY = nxtT.y;  // prefetched during previous row's epilogue
    int s = 0, S;
    int j1v = 0;                         // column selected at the previous step
    int recRow = 0, recCol = 0, recPrev = 0;   // thread t records step t's state
    double recU = 0.0, recD = 0.0;
    float recTX = 0.f, recTY = 0.f;

    for (;;) {
      // record this step's pre-state on thread s (off the dependency spine)
      if (tid == s) {
        recRow = i0; recU = ui0; recTX = tX; recTY = tY; recD = D; recPrev = j1v;
      }

      // scan my 8 columns: cur = ((double)cf - u[i0]) - v[j]; used columns
      // poisoned at the f32 stage (cf = +inf => cur = +inf, never wins)
      double cv[KPT];
#pragma unroll
      for (int k = 0; k < KPT; ++k) {
        float cf = fabsf(qx[k] - tX) + fabsf(qy[k] - tY) + np_[k];
        if (usedMask & (1u << k)) cf = FINF;
        cv[k] = ((double)cf - ui0) - vreg[k];
      }
      // within-lane argmin: fmin tree for the value, then parallel ==-mask +
      // ctz => smallest k among exact equals (first occurrence; +/-0 match)
      const double m01 = fmin(cv[0], cv[1]), m23 = fmin(cv[2], cv[3]);
      const double m45 = fmin(cv[4], cv[5]), m67 = fmin(cv[6], cv[7]);
      const double m03 = fmin(m01, m23), m47 = fmin(m45, m67);
      double bval = fmin(m03, m47);
      unsigned emsk = 0;
#pragma unroll
      for (int k = 0; k < KPT; ++k) emsk |= (cv[k] == bval) ? (1u << k) : 0u;
      const int bk = (int)__builtin_ctz(emsk);   // emsk != 0 always
      int bidx = 1 + tid + (bk << 8);

      // pre-barrier: read MY candidate's colDat (off the serial chain — its
      // ~130cy latency overlaps the DPP+ballot phase below; bank-clean:
      // 16B-stride in tid, bk*4096B offset is bank-aligned). colDat is
      // read-only during a row's steps, so this equals R11's post-barrier
      // read of the same column.
      const CD myCd = colDat[bidx];

      // monotonic u64 bit-key of the per-lane winner (canonicalize -0 -> +0)
      bval += 0.0;
      const long long bb = __double_as_longlong(bval);
      const unsigned long long key = (unsigned long long)bb ^
          ((bb < 0) ? 0xFFFFFFFFFFFFFFFFull : 0x8000000000000000ull);
      const unsigned khi = (unsigned)(key >> 32);
      const unsigned klo = (unsigned)key;

      // wave argmin: DPP min on hi32, ballot for winner, exact ties slow path
      const unsigned minhi = wave_min_u32_dpp(khi);
      const unsigned long long mask = __ballot(khi == minhi);
      int wl;
      if (__popcll(mask) == 1) {
        wl = (int)__ffsll(mask) - 1;
      } else {
        unsigned wklo = 0xffffffffu; int widx = 0x7fffffff; wl = 0;
        unsigned long long mm = mask;
        while (mm) {
          const int l = (int)__ffsll(mm) - 1; mm &= mm - 1;
          const unsigned lo2 = (unsigned)__builtin_amdgcn_readlane((int)klo, l);
          const int ix2 = __builtin_amdgcn_readlane(bidx, l);
          if (lo2 < wklo || (lo2 == wklo && ix2 < widx)) {
            wklo = lo2; widx = ix2; wl = l;
          }
        }
      }
      // the WINNING LANE writes keys + its candidate's colDat (32B, 2x b128)
      const int par = s & 1;
      if (lane == wl) {
        pk2[par][wv][0] = make_uint4(minhi, klo, (unsigned)bidx, 0u);
        const unsigned long long cu =
            (unsigned long long)__double_as_longlong(myCd.u);
        pk2[par][wv][1] = make_uint4((unsigned)cu, (unsigned)(cu >> 32),
                                     __float_as_uint(myCd.tx),
                                     __float_as_uint(myCd.ty));
      }
      __syncthreads();            // the only per-step barrier

      // read all 8 mailbox quads — INDEPENDENT uniform broadcast reads
      // (~130cy once, vs R11's pk -> dependent colDat = ~260cy)
      const uint4 c0v = pk2[par][0][0];
      const uint4 c1v = pk2[par][1][0];
      const uint4 c2v = pk2[par][2][0];
      const uint4 c3v = pk2[par][3][0];
      const uint4 d0v = pk2[par][0][1];
      const uint4 d1v = pk2[par][1][1];
      const uint4 d2v = pk2[par][2][1];
      const uint4 d3v = pk2[par][3][1];

      // cross-wave pairwise tournament (left wins ties at every level ==
      // same winner as the left-to-right scan of R5-R12)
      const unsigned long long k0b = ((unsigned long long)c0v.x << 32) | c0v.y;
      const unsigned long long k1b = ((unsigned long long)c1v.x << 32) | c1v.y;
      const unsigned long long k2b = ((unsigned long long)c2v.x << 32) | c2v.y;
      const unsigned long long k3b = ((unsigned long long)c3v.x << 32) | c3v.y;
      const int j0b = (int)c0v.z, j1bb = (int)c1v.z;
      const int j2b = (int)c2v.z, j3b = (int)c3v.z;
      // level 1 (pairs 01 and 23, independent)
      const bool w01 = (k1b < k0b) || (k1b == k0b && j1bb < j0b);
      const unsigned long long k01 = w01 ? k1b : k0b;
      const int j01 = w01 ? j1bb : j0b;
      const bool w23 = (k3b < k2b) || (k3b == k2b && j3b < j2b);
      const unsigned long long k23 = w23 ? k3b : k2b;
      const int j23 = w23 ? j3b : j2b;
      // level 2 (final)
      const bool wf = (k23 < k01) || (k23 == k01 && j23 < j01);
      const unsigned long long bkk = wf ? k23 : k01;
      const int j1 = wf ? j23 : j01;          // selected column, 1-based
      // cd folded along the same selectors in the u32 domain (12 cndmask;
      // values bitwise equal to R11's CD-struct fold of colDat reads)
      const unsigned ulA = w01 ? d1v.x : d0v.x, uhA = w01 ? d1v.y : d0v.y;
      const unsigned xAf = w01 ? d1v.z : d0v.z, yAf = w01 ? d1v.w : d0v.w;
      const unsigned ulB = w23 ? d3v.x : d2v.x, uhB = w23 ? d3v.y : d2v.y;
      const unsigned xBf = w23 ? d3v.z : d2v.z, yBf = w23 ? d3v.w : d2v.w;
      const unsigned ulW = wf ? ulB : ulA, uhW = wf ? uhB : uhA;
      const unsigned xW = wf ? xBf : xAf, yW = wf ? yBf : yAf;
      const double cdun = __longlong_as_double(
          (long long)(((unsigned long long)uhW << 32) | ulW));
      const float cdtx = __uint_as_float(xW);
      const float cdty = __uint_as_float(yW);

      // invert bit-key -> delta (bitwise identical on every thread)
      const long long db = (long long)((bkk & 0x8000000000000000ull)
                                           ? (bkk ^ 0x8000000000000000ull) : ~bkk);
      D += __longlong_as_double(db);
      if (tid == ((j1 - 1) & 255)) usedMask |= 1u << ((j1 - 1) >> 8);
      if (tid == s) recCol = j1;
      const int pj1 = (int)p[j1];   // off-path: feeds only next step's recorder
      j1v = j1;
      ++s;
      if (cdtx < 0.0f) { S = s; break; }   // free column => path complete
      ui0 = cdun; tX = cdtx; tY = cdty; i0 = pj1;
    }

    // ---- epilogue: O(path) deferred updates from recorded registers ----
    __syncthreads();              // E: all waves done stepping (protects the
                                  // final step's colDat reads vs writes below)
    nxtT = rowTgt[i < T ? i + 1 : T];   // prefetch next row's target (read-only)
    const double Dfin = D;
    if (tid < S) {
      p[recCol] = (short)recRow;                  // augment (rows/cols distinct)
      const double unew = recU + (Dfin - recD);   // same single-add as R3-R12
      CD c2; c2.u = unew; c2.tx = recTX; c2.ty = recTY;
      colDat[recCol] = c2;                        // refresh cache (tx >= 0)
      if (tid >= 1) {
        // column of step tid-1 (== visCol[tid]) receives Dfin - recD
        // (== Dfin - visD[tid]); path columns distinct => no collision
        vdelta[recPrev - 1] = Dfin - recD;
      }
    }
    __syncthreads();              // F: epilogue writes visible
    // owners apply their 8 slots: static indices, stride-8B conflict-free
    // reads; 0.0 slots are bitwise no-ops (x -= 0.0 == x, incl. -0.0).
#pragma unroll
    for (int k = 0; k < KPT; ++k) {
      const double dv = vdelta[tid + (k << 8)];
      vreg[k] -= dv;
      vdelta[tid + (k << 8)] = 0.0;   // reset; ordered vs next scatter by E
    }
    // next row's search reads (colDat/p) ordered by F; vdelta slots are
    // re-written only after the next E barrier
  }
  __syncthreads();

  // ---- extract assignment, rank-sort (distinct values), write int32 ----
  for (int j = 1 + tid; j <= Q; j += NT) {
    const int pi = (int)p[j];
    if (pi > 0) ansArr[pi - 1] = j - 1;
  }
  __syncthreads();
  const int a = ansArr[tid];
  int rank = 0;
  for (int t2 = 0; t2 < T; ++t2) rank += (ansArr[t2] < a) ? 1 : 0;
  out[(size_t)b * T + rank] = a;                      // row_ind (sorted query idx)
  out[(size_t)B * T + (size_t)b * T + rank] = tid;    // col_ind (target idx)
}

extern "C" void kernel_launch(void* const* d_in, const int* in_sizes, int n_in,
                              void* d_out, int out_size, void* d_ws, size_t ws_size,
                              hipStream_t stream) {
  const float* outs = (const float*)d_in[0];   // (8, 2048, 3) fp32
  const float* tgts = (const float*)d_in[1];   // (8, 256, 3) fp32
  int* out = (int*)d_out;                      // row_ind (8,256) ++ col_ind (8,256)
  hungarian_r14<<<B, NT, 0, stream>>>(outs, tgts, out);
}

// Round 6
// 861.538 us; speedup vs baseline: 1.3164x; 1.0036x over previous
//
#include <hip/hip_runtime.h>

// GPUHungarianMatcher R15 — exact replication of the reference's degenerate
// "_lsa" (minv reset every inner iteration => chain-Dijkstra). One block
// (4 waves) per batch. R15 = R14 (mailbox-cd spine: per-lane owner reads its
// OWN candidate's colDat pre-barrier, winning lane ships {keys|cd} through a
// 32B mailbox, post-barrier = 8 independent uniform b128 reads + tournament)
// + the barrier-graph thinning that R13 validated for correctness:
//  (1) barrier E deleted. Safe ONLY in the mailbox-cd structure: there are
//      NO post-barrier colDat reads, so the epilogue's colDat writes race
//      with nothing; the lone cross access (p[recCol] write vs a slow
//      wave's final-step p[j1] read) races on a DEAD value (pj1 -> i0 is
//      discarded on break).
//  (2) S==1 rows (step 0 hits a free column) skip scatter + barrier F + the
//      apply loop. The column OWNER thread ((j1-1)&255) writes
//      colDat[j1] = {D, tX, tY} and p[j1] = i:
//        * unew = recU + (Dfin - recD) = 0 + (D - 0) = D bitwise;
//        * tX/tY still hold row i's target (the state update is skipped on
//          break), i.e. recTX/recTY of step 0;
//        * the ONLY pre-barrier reader of colDat[j1] is the owner itself
//          (myCd = colDat[1 + tid + bk*256] is owner-read by construction),
//          same-thread LDS ordering via lgkmcnt;
//        * p[j1] is read by other waves only post-barrier; the owner's
//          write precedes its next-barrier arrival and __syncthreads drains
//          lgkmcnt before s_barrier => visible.
//  (3) mailbox parity is GLOBAL (toggles every step, never resets per row):
//      parity-slot reuse across barrier-less row boundaries would need a
//      wave 2 steps behind — impossible with one barrier per step.
//
// Exactness invariants (unchanged from the R2-R14 absmax-0 lineage):
//  * cost fp32: fabsf(qx-tX)+fabsf(qy-tY)+np_, reduced fp64: ((double)cf-u)-v
//  * scans read only PRE-search u/v; colDat is read during a row's steps
//    only by column owners and written only at row ends (ordered by F for
//    S>1, by same-thread program order for S==1)
//  * argmin: fmin + smallest-k among exact equals (ctz of ==-mask) =
//    np.argmin first occurrence; +inf f32 poison for used columns;
//    a wave can never be all-used (used < 256 < 512 cols/wave)
//  * pairwise tournament: left wins ties at every level => same winner as
//    the left-to-right scan (min + earliest index, keys lexicographic);
//    cd folded along the same selectors in the u32 domain = bitwise equal
//  * u update: single add of prefix-difference on pre-search u (recU)
//  * v update: vdelta scatter, values bitwise-identical to the serial loop
//  * softmax bitwise-identical to the R2 tree (same thread mapping)
//  * free-flag: colDat[j].tx = -1.0f iff column j unmatched (real tx >= 0)

constexpr int B = 8;
constexpr int Q = 2048;        // columns (queries)
constexpr int T = 256;         // rows (targets)
constexpr int NT = 256;        // threads per block (4 waves)
constexpr int KPT = Q / NT;    // 8 columns per thread, j = 1 + tid + k*256
constexpr int NW = NT / 64;

struct __align__(16) CD { double u; float tx, ty; };   // one ds_read_b128

__device__ __forceinline__ unsigned wave_min_u32_dpp(unsigned a) {
  // full-wave u32 min: row_shr 1,2,4,8 then row_bcast15, row_bcast31;
  // invalid source lanes keep old (bound_ctrl=false, masks 0xf) = identity.
  int v = (int)a, t;
  t = __builtin_amdgcn_update_dpp(v, v, 0x111, 0xf, 0xf, false);
  v = ((unsigned)t < (unsigned)v) ? t : v;
  t = __builtin_amdgcn_update_dpp(v, v, 0x112, 0xf, 0xf, false);
  v = ((unsigned)t < (unsigned)v) ? t : v;
  t = __builtin_amdgcn_update_dpp(v, v, 0x114, 0xf, 0xf, false);
  v = ((unsigned)t < (unsigned)v) ? t : v;
  t = __builtin_amdgcn_update_dpp(v, v, 0x118, 0xf, 0xf, false);
  v = ((unsigned)t < (unsigned)v) ? t : v;
  t = __builtin_amdgcn_update_dpp(v, v, 0x142, 0xf, 0xf, false);
  v = ((unsigned)t < (unsigned)v) ? t : v;
  t = __builtin_amdgcn_update_dpp(v, v, 0x143, 0xf, 0xf, false);
  v = ((unsigned)t < (unsigned)v) ? t : v;
  return (unsigned)__builtin_amdgcn_readlane(v, 63);   // lane 63 = global min
}

__launch_bounds__(NT, 1)
__global__ void hungarian_r15(const float* __restrict__ outs,
                              const float* __restrict__ tgts,
                              int* __restrict__ out) {
  const int b = blockIdx.x;
  const int tid = threadIdx.x;
  const int lane = tid & 63;
  const int wv = tid >> 6;

  __shared__ CD colDat[Q + 1];      // colDat[j] = {u[p[j]], tx[p[j]-1], ty[p[j]-1]}
                                    // tx = -1.0f marks a FREE column
  __shared__ float2 rowTgt[T + 1];  // rowTgt[r] = {tx[r-1], ty[r-1]} (read-only)
  __shared__ short p[Q + 1];        // p[j]: row matched to col j (1-based), 0 free
  __shared__ uint4 pk2[2][NW][2];   // mailbox (GLOBAL parity):
                                    //   [.][w][0] = {khi, klo, bidx, 0}
                                    //   [.][w][1] = {u_lo, u_hi, tx, ty}
  __shared__ double vdelta[Q];      // per-column v-delta scatter; 0.0 = no update
  __shared__ int ansArr[T];
  __shared__ double s_rv[NW];
  __shared__ float sh_f;

  const size_t qbase = (size_t)b * Q;
  const size_t tbase = (size_t)b * T;

  // ---- stage per-thread column data (fixed mapping j = 1 + tid + k*256) ----
  float xs[KPT], qx[KPT], qy[KPT];
#pragma unroll
  for (int k = 0; k < KPT; ++k) {
    const size_t o = (qbase + tid + k * NT) * 3;
    xs[k] = outs[o];
    qx[k] = outs[o + 1];
    qy[k] = outs[o + 2];
  }
  {
    const size_t o = (tbase + tid) * 3;   // T == NT: one target per thread
    rowTgt[tid + 1] = make_float2(tgts[o + 1], tgts[o + 2]);
    if (tid == 0) rowTgt[0] = make_float2(0.f, 0.f);
  }

  // ---- softmax over Q logits (bitwise-identical to the R2-passing tree) ----
  float lmax = xs[0];
#pragma unroll
  for (int k = 1; k < KPT; ++k) lmax = fmaxf(lmax, xs[k]);
  for (int off = 32; off > 0; off >>= 1) lmax = fmaxf(lmax, __shfl_down(lmax, off));
  if ((tid & 63) == 0) s_rv[tid >> 6] = (double)lmax;
  __syncthreads();
  if (tid == 0) {
    float m2 = (float)s_rv[0];
    for (int w = 1; w < NW; ++w) m2 = fmaxf(m2, (float)s_rv[w]);
    sh_f = m2;
  }
  __syncthreads();
  const float smax = sh_f;
  float ex[KPT];
  float lsum = 0.f;
#pragma unroll
  for (int k = 0; k < KPT; ++k) { ex[k] = expf(xs[k] - smax); lsum += ex[k]; }
  for (int off = 32; off > 0; off >>= 1) lsum += __shfl_down(lsum, off);
  if ((tid & 63) == 0) s_rv[tid >> 6] = (double)lsum;
  __syncthreads();
  if (tid == 0) {
    float s2 = 0.f;
    for (int w = 0; w < NW; ++w) s2 += (float)s_rv[w];
    sh_f = s2;
  }
  __syncthreads();
  const float ssum = sh_f;
  float np_[KPT];
#pragma unroll
  for (int k = 0; k < KPT; ++k) np_[k] = -(ex[k] / ssum);

  // ---- init state ----
  for (int j = tid; j <= Q; j += NT) {
    p[j] = 0;
    CD c0; c0.u = 0.0; c0.tx = -1.0f; c0.ty = 0.0f;   // all columns free
    colDat[j] = c0;
  }
  double vreg[KPT];   // v[j] for this thread's 8 columns (static indices only)
#pragma unroll
  for (int k = 0; k < KPT; ++k) {
    vreg[k] = 0.0;
    vdelta[tid + (k << 8)] = 0.0;
  }
  __syncthreads();

  const float FINF = __int_as_float(0x7f800000);   // +inf poison for used cols
  float2 nxtT = rowTgt[1];                         // prefetch row 1's target
  int par = 0;                                     // GLOBAL mailbox parity

  // ---- main loop over rows ----
  for (int i = 1; i <= T; ++i) {
    unsigned usedMask = 0;
    double D = 0.0;
    int i0 = i;
    double ui0 = 0.0;                // u[i] == 0 at row i's search start (R12)
    float tX = nxtT.x, tY = nxtT.y;  // prefetched during previous row's tail
    int s = 0, S;
    int j1v = 0;                         // column selected at the previous step
    int recRow = 0, recCol = 0, recPrev = 0;   // thread t records step t's state
    double recU = 0.0, recD = 0.0;
    float recTX = 0.f, recTY = 0.f;

    for (;;) {
      const int cpar = par; par ^= 1;   // global parity (uniform: lockstep)

      // record this step's pre-state on thread s (off the dependency spine)
      if (tid == s) {
        recRow = i0; recU = ui0; recTX = tX; recTY = tY; recD = D; recPrev = j1v;
      }

      // scan my 8 columns: cur = ((double)cf - u[i0]) - v[j]; used columns
      // poisoned at the f32 stage (cf = +inf => cur = +inf, never wins)
      double cv[KPT];
#pragma unroll
      for (int k = 0; k < KPT; ++k) {
        float cf = fabsf(qx[k] - tX) + fabsf(qy[k] - tY) + np_[k];
        if (usedMask & (1u << k)) cf = FINF;
        cv[k] = ((double)cf - ui0) - vreg[k];
      }
      // within-lane argmin: fmin tree for the value, then parallel ==-mask +
      // ctz => smallest k among exact equals (first occurrence; +/-0 match)
      const double m01 = fmin(cv[0], cv[1]), m23 = fmin(cv[2], cv[3]);
      const double m45 = fmin(cv[4], cv[5]), m67 = fmin(cv[6], cv[7]);
      const double m03 = fmin(m01, m23), m47 = fmin(m45, m67);
      double bval = fmin(m03, m47);
      unsigned emsk = 0;
#pragma unroll
      for (int k = 0; k < KPT; ++k) emsk |= (cv[k] == bval) ? (1u << k) : 0u;
      const int bk = (int)__builtin_ctz(emsk);   // emsk != 0 always
      int bidx = 1 + tid + (bk << 8);

      // pre-barrier: read MY candidate's colDat (this thread OWNS column
      // bidx). Off the serial chain — latency overlaps the DPP+ballot phase.
      // colDat[bidx] writes are ordered: F barrier (S>1 rows) or same-thread
      // program order (S==1 rows, owner-write/owner-read).
      const CD myCd = colDat[bidx];

      // monotonic u64 bit-key of the per-lane winner (canonicalize -0 -> +0)
      bval += 0.0;
      const long long bb = __double_as_longlong(bval);
      const unsigned long long key = (unsigned long long)bb ^
          ((bb < 0) ? 0xFFFFFFFFFFFFFFFFull : 0x8000000000000000ull);
      const unsigned khi = (unsigned)(key >> 32);
      const unsigned klo = (unsigned)key;

      // wave argmin: DPP min on hi32, ballot for winner, exact ties slow path
      const unsigned minhi = wave_min_u32_dpp(khi);
      const unsigned long long mask = __ballot(khi == minhi);
      int wl;
      if (__popcll(mask) == 1) {
        wl = (int)__ffsll(mask) - 1;
      } else {
        unsigned wklo = 0xffffffffu; int widx = 0x7fffffff; wl = 0;
        unsigned long long mm = mask;
        while (mm) {
          const int l = (int)__ffsll(mm) - 1; mm &= mm - 1;
          const unsigned lo2 = (unsigned)__builtin_amdgcn_readlane((int)klo, l);
          const int ix2 = __builtin_amdgcn_readlane(bidx, l);
          if (lo2 < wklo || (lo2 == wklo && ix2 < widx)) {
            wklo = lo2; widx = ix2; wl = l;
          }
        }
      }
      // the WINNING LANE writes keys + its candidate's colDat (32B, 2x b128)
      if (lane == wl) {
        pk2[cpar][wv][0] = make_uint4(minhi, klo, (unsigned)bidx, 0u);
        const unsigned long long cu =
            (unsigned long long)__double_as_longlong(myCd.u);
        pk2[cpar][wv][1] = make_uint4((unsigned)cu, (unsigned)(cu >> 32),
                                      __float_as_uint(myCd.tx),
                                      __float_as_uint(myCd.ty));
      }
      __syncthreads();            // the only per-step barrier

      // read all 8 mailbox quads — INDEPENDENT uniform broadcast reads
      const uint4 c0v = pk2[cpar][0][0];
      const uint4 c1v = pk2[cpar][1][0];
      const uint4 c2v = pk2[cpar][2][0];
      const uint4 c3v = pk2[cpar][3][0];
      const uint4 d0v = pk2[cpar][0][1];
      const uint4 d1v = pk2[cpar][1][1];
      const uint4 d2v = pk2[cpar][2][1];
      const uint4 d3v = pk2[cpar][3][1];

      // cross-wave pairwise tournament (left wins ties at every level ==
      // same winner as the left-to-right scan of R5-R14)
      const unsigned long long k0b = ((unsigned long long)c0v.x << 32) | c0v.y;
      const unsigned long long k1b = ((unsigned long long)c1v.x << 32) | c1v.y;
      const unsigned long long k2b = ((unsigned long long)c2v.x << 32) | c2v.y;
      const unsigned long long k3b = ((unsigned long long)c3v.x << 32) | c3v.y;
      const int j0b = (int)c0v.z, j1bb = (int)c1v.z;
      const int j2b = (int)c2v.z, j3b = (int)c3v.z;
      // level 1 (pairs 01 and 23, independent)
      const bool w01 = (k1b < k0b) || (k1b == k0b && j1bb < j0b);
      const unsigned long long k01 = w01 ? k1b : k0b;
      const int j01 = w01 ? j1bb : j0b;
      const bool w23 = (k3b < k2b) || (k3b == k2b && j3b < j2b);
      const unsigned long long k23 = w23 ? k3b : k2b;
      const int j23 = w23 ? j3b : j2b;
      // level 2 (final)
      const bool wf = (k23 < k01) || (k23 == k01 && j23 < j01);
      const unsigned long long bkk = wf ? k23 : k01;
      const int j1 = wf ? j23 : j01;          // selected column, 1-based
      // cd folded along the same selectors in the u32 domain (12 cndmask)
      const unsigned ulA = w01 ? d1v.x : d0v.x, uhA = w01 ? d1v.y : d0v.y;
      const unsigned xAf = w01 ? d1v.z : d0v.z, yAf = w01 ? d1v.w : d0v.w;
      const unsigned ulB = w23 ? d3v.x : d2v.x, uhB = w23 ? d3v.y : d2v.y;
      const unsigned xBf = w23 ? d3v.z : d2v.z, yBf = w23 ? d3v.w : d2v.w;
      const unsigned ulW = wf ? ulB : ulA, uhW = wf ? uhB : uhA;
      const unsigned xW = wf ? xBf : xAf, yW = wf ? yBf : yAf;
      const double cdun = __longlong_as_double(
          (long long)(((unsigned long long)uhW << 32) | ulW));
      const float cdtx = __uint_as_float(xW);
      const float cdty = __uint_as_float(yW);

      // invert bit-key -> delta (bitwise identical on every thread)
      const long long db = (long long)((bkk & 0x8000000000000000ull)
                                           ? (bkk ^ 0x8000000000000000ull) : ~bkk);
      D += __longlong_as_double(db);
      if (tid == ((j1 - 1) & 255)) usedMask |= 1u << ((j1 - 1) >> 8);
      if (tid == s) recCol = j1;
      const int pj1 = (int)p[j1];   // off-path: feeds only next step's recorder
                                    // (dead value on the final step)
      j1v = j1;
      ++s;
      if (cdtx < 0.0f) { S = s; break; }   // free column => path complete
      ui0 = cdun; tX = cdtx; tY = cdty; i0 = pj1;
    }

    // ---- row tail: NO barrier E (waves lockstep; mailbox-only post-barrier
    // reads make the epilogue's colDat/p writes race-free — header proof) ----
    nxtT = rowTgt[i < T ? i + 1 : T];   // prefetch next row's target (read-only)
    if (S == 1) {
      // fast path: step 0 hit a free column. unew = 0 + (D - 0) = D bitwise;
      // tX/tY still hold row i's target (state update skipped on break).
      // The column OWNER writes its own colDat + p: the only pre-barrier
      // reader of colDat[j1v] is the owner itself (same-thread ordering);
      // p[j1v] is read by others only post-next-barrier (lgkmcnt drained).
      const int c = j1v - 1;
      if (tid == (c & 255)) {
        p[j1v] = (short)i;
        CD c2; c2.u = D; c2.tx = tX; c2.ty = tY;
        colDat[j1v] = c2;
      }
      // no scatter slots touched; no barrier, no apply loop
    } else {
      const double Dfin = D;
      if (tid < S) {
        p[recCol] = (short)recRow;                  // augment (rows/cols distinct)
        const double unew = recU + (Dfin - recD);   // same single-add as R3-R14
        CD c2; c2.u = unew; c2.tx = recTX; c2.ty = recTY;
        colDat[recCol] = c2;                        // refresh cache (tx >= 0)
        if (tid >= 1) {
          // column of step tid-1 (== visCol[tid]) receives Dfin - recD
          // (== Dfin - visD[tid]); path columns distinct => no collision
          vdelta[recPrev - 1] = Dfin - recD;
        }
      }
      __syncthreads();              // F: epilogue writes visible
      // owners apply their 8 slots: static indices, stride-8B conflict-free
      // reads; 0.0 slots are bitwise no-ops (x -= 0.0 == x, incl. -0.0).
#pragma unroll
      for (int k = 0; k < KPT; ++k) {
        const double dv = vdelta[tid + (k << 8)];
        vreg[k] -= dv;
        vdelta[tid + (k << 8)] = 0.0;   // reset; ordered vs next scatter by
                                        // the next row's step barriers
      }
    }
  }
  __syncthreads();

  // ---- extract assignment, rank-sort (distinct values), write int32 ----
  for (int j = 1 + tid; j <= Q; j += NT) {
    const int pi = (int)p[j];
    if (pi > 0) ansArr[pi - 1] = j - 1;
  }
  __syncthreads();
  const int a = ansArr[tid];
  int rank = 0;
  for (int t2 = 0; t2 < T; ++t2) rank += (ansArr[t2] < a) ? 1 : 0;
  out[(size_t)b * T + rank] = a;                      // row_ind (sorted query idx)
  out[(size_t)B * T + (size_t)b * T + rank] = tid;    // col_ind (target idx)
}

extern "C" void kernel_launch(void* const* d_in, const int* in_sizes, int n_in,
                              void* d_out, int out_size, void* d_ws, size_t ws_size,
                              hipStream_t stream) {
  const float* outs = (const float*)d_in[0];   // (8, 2048, 3) fp32
  const float* tgts = (const float*)d_in[1];   // (8, 256, 3) fp32
  int* out = (int*)d_out;                      // row_ind (8,256) ++ col_ind (8,256)
  hungarian_r15<<<B, NT, 0, stream>>>(outs, tgts, out);
}